// Round 1
// baseline (790.153 us; speedup 1.0000x reference)
//
#include <hip/hip_runtime.h>
#include <hip/hip_bf16.h>
#include <math.h>

#define IN_DIM 256
#define HD     512   // NUM_HEADS * OUT_DIM
#define NHEADS 8
#define DH     64    // per-head dim
#define NSEQ   1024
#define BATCH  8

// ============================================================
// Kernel 1: fused QKV projection GEMM.  M=8192, K=256, N=512 x3
// 64x64 tile, BK=16, 256 threads, 4x4 microtile per thread.
// ============================================================
#define GBM 64
#define GBN 64
#define GBK 16

__global__ __launch_bounds__(256)
void qkv_gemm_kernel(const float* __restrict__ h,
                     const float* __restrict__ Wq, const float* __restrict__ bq,
                     const float* __restrict__ Wk, const float* __restrict__ bk,
                     const float* __restrict__ Wv, const float* __restrict__ bv,
                     float* __restrict__ Qg, float* __restrict__ Kg,
                     float* __restrict__ Vg)
{
    __shared__ float As[GBM][GBK + 1];
    __shared__ float Bs[GBK][GBN + 1];

    const int m0 = blockIdx.x * GBM;
    const int nt = blockIdx.y;          // 0..23 : 8 n-tiles per weight
    const int which = nt >> 3;
    const int n0 = (nt & 7) * GBN;

    const float* W;
    const float* bias;
    float* Out;
    if (which == 0)      { W = Wq; bias = bq; Out = Qg; }
    else if (which == 1) { W = Wk; bias = bk; Out = Kg; }
    else                 { W = Wv; bias = bv; Out = Vg; }

    const int tid = threadIdx.x;
    const int tm = (tid >> 4) * 4;      // 0..60
    const int tn = (tid & 15) * 4;      // 0..60

    const int la_row = tid >> 2;        // 0..63
    const int la_col = (tid & 3) * 4;   // 0,4,8,12
    const int lb_row = tid >> 4;        // 0..15
    const int lb_col = (tid & 15) * 4;  // 0..60

    float acc[4][4] = {{0.f, 0.f, 0.f, 0.f}, {0.f, 0.f, 0.f, 0.f},
                       {0.f, 0.f, 0.f, 0.f}, {0.f, 0.f, 0.f, 0.f}};

    for (int k0 = 0; k0 < IN_DIM; k0 += GBK) {
        float4 av = *(const float4*)(h + (size_t)(m0 + la_row) * IN_DIM + k0 + la_col);
        float4 bw = *(const float4*)(W + (size_t)(k0 + lb_row) * HD + n0 + lb_col);
        As[la_row][la_col + 0] = av.x;
        As[la_row][la_col + 1] = av.y;
        As[la_row][la_col + 2] = av.z;
        As[la_row][la_col + 3] = av.w;
        Bs[lb_row][lb_col + 0] = bw.x;
        Bs[lb_row][lb_col + 1] = bw.y;
        Bs[lb_row][lb_col + 2] = bw.z;
        Bs[lb_row][lb_col + 3] = bw.w;
        __syncthreads();
#pragma unroll
        for (int k = 0; k < GBK; ++k) {
            float a0 = As[tm + 0][k], a1 = As[tm + 1][k];
            float a2 = As[tm + 2][k], a3 = As[tm + 3][k];
            float b0 = Bs[k][tn + 0], b1 = Bs[k][tn + 1];
            float b2 = Bs[k][tn + 2], b3 = Bs[k][tn + 3];
            acc[0][0] += a0 * b0; acc[0][1] += a0 * b1; acc[0][2] += a0 * b2; acc[0][3] += a0 * b3;
            acc[1][0] += a1 * b0; acc[1][1] += a1 * b1; acc[1][2] += a1 * b2; acc[1][3] += a1 * b3;
            acc[2][0] += a2 * b0; acc[2][1] += a2 * b1; acc[2][2] += a2 * b2; acc[2][3] += a2 * b3;
            acc[3][0] += a3 * b0; acc[3][1] += a3 * b1; acc[3][2] += a3 * b2; acc[3][3] += a3 * b3;
        }
        __syncthreads();
    }

    float4 biasv = *(const float4*)(bias + n0 + tn);
#pragma unroll
    for (int i = 0; i < 4; ++i) {
        float4 o;
        o.x = acc[i][0] + biasv.x;
        o.y = acc[i][1] + biasv.y;
        o.z = acc[i][2] + biasv.z;
        o.w = acc[i][3] + biasv.w;
        *(float4*)(Out + (size_t)(m0 + tm + i) * HD + n0 + tn) = o;
    }
}

// ============================================================
// Kernel 2: fused masked attention (flash-style online softmax)
// grid = (16 q-tiles, 64 b*h), 256 threads.
// Per block: 64 queries x all 1024 keys in 64-key chunks.
// ============================================================
#define QT 64   // queries per block
#define CT 64   // keys per chunk
#define SP 68   // padded LDS row stride (floats), keeps 16B alignment

__global__ __launch_bounds__(256)
void attn_kernel(const int* __restrict__ adj,
                 const float* __restrict__ Qg, const float* __restrict__ Kg,
                 const float* __restrict__ Vg, float* __restrict__ out)
{
    __shared__ float Qs[QT][SP];
    __shared__ float Ks[CT][SP];
    __shared__ float Vs[CT][SP];
    __shared__ float Ss[CT][SP];       // scores, then p, stored [m][q]
    __shared__ float pred[4][QT];      // partial max / partial sum
    __shared__ float mstate[QT], lstate[QT], alpha_s[QT], mref_s[QT];

    const int tid = threadIdx.x;
    const int qt  = blockIdx.x;        // 0..15
    const int bh  = blockIdx.y;        // 0..63
    const int b   = bh >> 3;
    const int hh  = bh & 7;

    const int n0 = qt * QT;
    const size_t rowbase = (size_t)b * NSEQ;
    const int colbase = hh * DH;

    // stage Q tile (pre-scaled by 1/sqrt(D) = 0.125, exact pow2)
#pragma unroll
    for (int it = 0; it < 4; ++it) {
        int f = tid + it * 256;        // 0..1023
        int r = f >> 4;
        int c = (f & 15) * 4;
        float4 v = *(const float4*)(Qg + (rowbase + n0 + r) * HD + colbase + c);
        Qs[r][c + 0] = v.x * 0.125f;
        Qs[r][c + 1] = v.y * 0.125f;
        Qs[r][c + 2] = v.z * 0.125f;
        Qs[r][c + 3] = v.w * 0.125f;
    }
    if (tid < QT) { mstate[tid] = -INFINITY; lstate[tid] = 0.f; }

    // score-phase mapping: q = 4*sq+i, m = sm+16*j
    const int sq = tid >> 4;           // 0..15
    const int sm = tid & 15;           // 0..15
    // PV-phase mapping: q = 4*qq+i, d = 4*dg+j
    const int qq = tid >> 4;
    const int dg = tid & 15;
    const int q0 = qq * 4;
    const int d0 = dg * 4;

    float O[4][4] = {{0.f, 0.f, 0.f, 0.f}, {0.f, 0.f, 0.f, 0.f},
                     {0.f, 0.f, 0.f, 0.f}, {0.f, 0.f, 0.f, 0.f}};

    for (int ch = 0; ch < NSEQ / CT; ++ch) {
        const int m0 = ch * CT;
        __syncthreads();   // previous chunk's PV (Ss/Vs readers) done

        // stage K and V chunk
#pragma unroll
        for (int it = 0; it < 4; ++it) {
            int f = tid + it * 256;
            int r = f >> 4;
            int c = (f & 15) * 4;
            const size_t g = (rowbase + m0 + r) * HD + colbase + c;
            float4 kv = *(const float4*)(Kg + g);
            float4 vv = *(const float4*)(Vg + g);
            Ks[r][c + 0] = kv.x; Ks[r][c + 1] = kv.y;
            Ks[r][c + 2] = kv.z; Ks[r][c + 3] = kv.w;
            Vs[r][c + 0] = vv.x; Vs[r][c + 1] = vv.y;
            Vs[r][c + 2] = vv.z; Vs[r][c + 3] = vv.w;
        }
        __syncthreads();

        // scores: s[i][j] = Qs[4sq+i][:] . Ks[sm+16j][:]
        float s[4][4] = {{0.f, 0.f, 0.f, 0.f}, {0.f, 0.f, 0.f, 0.f},
                         {0.f, 0.f, 0.f, 0.f}, {0.f, 0.f, 0.f, 0.f}};
#pragma unroll
        for (int k = 0; k < DH; k += 4) {
            float4 qv[4], kv[4];
#pragma unroll
            for (int i = 0; i < 4; ++i) qv[i] = *(const float4*)&Qs[4 * sq + i][k];
#pragma unroll
            for (int j = 0; j < 4; ++j) kv[j] = *(const float4*)&Ks[sm + 16 * j][k];
#pragma unroll
            for (int i = 0; i < 4; ++i)
#pragma unroll
                for (int j = 0; j < 4; ++j)
                    s[i][j] += qv[i].x * kv[j].x + qv[i].y * kv[j].y +
                               qv[i].z * kv[j].z + qv[i].w * kv[j].w;
        }
        // mask via adjacency, write S^T to LDS
#pragma unroll
        for (int i = 0; i < 4; ++i) {
#pragma unroll
            for (int j = 0; j < 4; ++j) {
                int a = adj[(size_t)(n0 + 4 * sq + i) * NSEQ + m0 + sm + 16 * j];
                if (a == 0) s[i][j] = -INFINITY;
                Ss[sm + 16 * j][4 * sq + i] = s[i][j];
            }
        }
        __syncthreads();

        // per-q chunk max (4 workers per q)
        {
            int q = tid & 63, part = tid >> 6;
            float mx = -INFINITY;
#pragma unroll
            for (int it = 0; it < 16; ++it) mx = fmaxf(mx, Ss[part * 16 + it][q]);
            pred[part][q] = mx;
        }
        __syncthreads();
        if (tid < QT) {
            float cm = fmaxf(fmaxf(pred[0][tid], pred[1][tid]),
                             fmaxf(pred[2][tid], pred[3][tid]));
            float mold = mstate[tid];
            float mnew = fmaxf(mold, cm);
            float alpha = (mold == -INFINITY) ? 0.f : __expf(mold - mnew);
            mstate[tid]  = mnew;
            lstate[tid] *= alpha;
            alpha_s[tid] = alpha;
            mref_s[tid]  = (mnew == -INFINITY) ? 0.f : mnew;  // guard all-masked chunk
        }
        __syncthreads();

        // p = exp(s - m_new) from registers, overwrite Ss
#pragma unroll
        for (int i = 0; i < 4; ++i) {
            float mr = mref_s[4 * sq + i];
#pragma unroll
            for (int j = 0; j < 4; ++j)
                Ss[sm + 16 * j][4 * sq + i] = __expf(s[i][j] - mr);
        }
        __syncthreads();

        // per-q chunk sum
        {
            int q = tid & 63, part = tid >> 6;
            float sum = 0.f;
#pragma unroll
            for (int it = 0; it < 16; ++it) sum += Ss[part * 16 + it][q];
            pred[part][q] = sum;
        }
        __syncthreads();
        if (tid < QT)
            lstate[tid] += pred[0][tid] + pred[1][tid] + pred[2][tid] + pred[3][tid];

        // PV: O[q][d] (rescaled by alpha) += sum_m p[m][q] * V[m][d]
        float a[4];
#pragma unroll
        for (int i = 0; i < 4; ++i) a[i] = alpha_s[q0 + i];
#pragma unroll
        for (int i = 0; i < 4; ++i)
#pragma unroll
            for (int j = 0; j < 4; ++j) O[i][j] *= a[i];
#pragma unroll 8
        for (int m = 0; m < CT; ++m) {
            float4 pv = *(const float4*)&Ss[m][q0];
            float4 vv = *(const float4*)&Vs[m][d0];
            O[0][0] += pv.x * vv.x; O[0][1] += pv.x * vv.y; O[0][2] += pv.x * vv.z; O[0][3] += pv.x * vv.w;
            O[1][0] += pv.y * vv.x; O[1][1] += pv.y * vv.y; O[1][2] += pv.y * vv.z; O[1][3] += pv.y * vv.w;
            O[2][0] += pv.z * vv.x; O[2][1] += pv.z * vv.y; O[2][2] += pv.z * vv.z; O[2][3] += pv.z * vv.w;
            O[3][0] += pv.w * vv.x; O[3][1] += pv.w * vv.y; O[3][2] += pv.w * vv.z; O[3][3] += pv.w * vv.w;
        }
    }
    __syncthreads();
    if (tid < QT) alpha_s[tid] = 1.0f / lstate[tid];   // reuse as inv_l
    __syncthreads();

#pragma unroll
    for (int i = 0; i < 4; ++i) {
        float inv = alpha_s[q0 + i];
        float4 o;
        o.x = O[i][0] * inv;
        o.y = O[i][1] * inv;
        o.z = O[i][2] * inv;
        o.w = O[i][3] * inv;
        *(float4*)(out + (rowbase + n0 + q0 + i) * HD + colbase + d0) = o;
    }
}

// ============================================================
extern "C" void kernel_launch(void* const* d_in, const int* in_sizes, int n_in,
                              void* d_out, int out_size, void* d_ws, size_t ws_size,
                              hipStream_t stream) {
    const int*   adj = (const int*)d_in[0];
    const float* h   = (const float*)d_in[1];
    const float* Wq  = (const float*)d_in[2];
    const float* bq  = (const float*)d_in[3];
    const float* Wk  = (const float*)d_in[4];
    const float* bk  = (const float*)d_in[5];
    const float* Wv  = (const float*)d_in[6];
    const float* bv  = (const float*)d_in[7];
    float* outp = (float*)d_out;

    const size_t mat_elems = (size_t)BATCH * NSEQ * HD;   // 4 Mi floats = 16 MB
    float* Qg = (float*)d_ws;
    float* Kg = Qg + mat_elems;
    float* Vg = Kg + mat_elems;

    dim3 gridG(BATCH * NSEQ / GBM, 24);   // 128 x 24
    qkv_gemm_kernel<<<gridG, 256, 0, stream>>>(h, Wq, bq, Wk, bk, Wv, bv, Qg, Kg, Vg);

    dim3 gridA(NSEQ / QT, BATCH * NHEADS);  // 16 x 64
    attn_kernel<<<gridA, 256, 0, stream>>>(adj, Qg, Kg, Vg, outp);
}

// Round 2
// 167.963 us; speedup vs baseline: 4.7043x; 4.7043x over previous
//
#include <hip/hip_runtime.h>
#include <math.h>

#define IN_DIM 256
#define HD     512   // NUM_HEADS * OUT_DIM
#define NHEADS 8
#define DH     64
#define NSEQ   1024
#define BATCH  8

typedef unsigned short u16;
typedef short bf16x8 __attribute__((ext_vector_type(8)));
typedef float f32x4  __attribute__((ext_vector_type(4)));

static __device__ __forceinline__ u16 f2bf(float x) {
    unsigned u = __builtin_bit_cast(unsigned, x);
    u += 0x7FFFu + ((u >> 16) & 1u);     // RNE
    return (u16)(u >> 16);
}
static __device__ __forceinline__ unsigned pk(u16 a, u16 b) {
    return (unsigned)a | ((unsigned)b << 16);
}

// ============================================================
// Prep 1: h fp32 -> bf16
// ============================================================
__global__ __launch_bounds__(256)
void cvt_h_kernel(const float* __restrict__ h, u16* __restrict__ h_bf) {
    int i = (blockIdx.x * 256 + threadIdx.x) * 4;
    float4 v = *(const float4*)(h + i);
    ushort4 o;
    o.x = f2bf(v.x); o.y = f2bf(v.y); o.z = f2bf(v.z); o.w = f2bf(v.w);
    *(ushort4*)(h_bf + i) = o;
}

// ============================================================
// Prep 2: W [K=256][N=512] fp32 -> Wt [N=512][K=256] bf16 (x3)
// ============================================================
__global__ __launch_bounds__(256)
void wtrans_kernel(const float* __restrict__ Wq, const float* __restrict__ Wk,
                   const float* __restrict__ Wv, u16* __restrict__ Wt) {
    __shared__ float tile[64][65];
    const int k0 = blockIdx.x * 64;       // 0..3
    const int n0 = blockIdx.y * 64;       // 0..7
    const int wsel = blockIdx.z;          // 0..2
    const float* W = (wsel == 0) ? Wq : (wsel == 1) ? Wk : Wv;
    u16* Out = Wt + (size_t)wsel * HD * IN_DIM;

    const int r = threadIdx.x >> 2, c0 = (threadIdx.x & 3) * 16;
#pragma unroll
    for (int j = 0; j < 16; j += 4) {
        float4 v = *(const float4*)(W + (size_t)(k0 + r) * HD + n0 + c0 + j);
        tile[r][c0 + j + 0] = v.x; tile[r][c0 + j + 1] = v.y;
        tile[r][c0 + j + 2] = v.z; tile[r][c0 + j + 3] = v.w;
    }
    __syncthreads();
    const int n = threadIdx.x >> 2, ks = (threadIdx.x & 3) * 16;
    u16 o[16];
#pragma unroll
    for (int j = 0; j < 16; ++j) o[j] = f2bf(tile[ks + j][n]);
    uint4 u0, u1;
    u0.x = pk(o[0], o[1]);  u0.y = pk(o[2], o[3]);
    u0.z = pk(o[4], o[5]);  u0.w = pk(o[6], o[7]);
    u1.x = pk(o[8], o[9]);  u1.y = pk(o[10], o[11]);
    u1.z = pk(o[12], o[13]); u1.w = pk(o[14], o[15]);
    u16* dst = Out + (size_t)(n0 + n) * IN_DIM + k0 + ks;
    *(uint4*)(dst) = u0;
    *(uint4*)(dst + 8) = u1;
}

// ============================================================
// QKV GEMM, bf16 MFMA 16x16x32.  64x64 tile, 256 thr (4 waves).
// Q written pre-scaled by 0.125; V written transposed [b][h][d][n].
// ============================================================
#define GP 40   // LDS k-stride (u16): 20 dwords -> conflict-light frags

__global__ __launch_bounds__(256)
void qkv_gemm_kernel(const u16* __restrict__ h_bf, const u16* __restrict__ Wt,
                     const float* __restrict__ bq, const float* __restrict__ bk,
                     const float* __restrict__ bv,
                     u16* __restrict__ Qg, u16* __restrict__ Kg,
                     u16* __restrict__ Vtg)
{
    __shared__ u16 pool[2 * 64 * GP];   // As | Bs ; reused as T[64][72]
    u16* As = pool;
    u16* Bs = pool + 64 * GP;

    const int m0 = blockIdx.x * 64;
    const int nt = blockIdx.y;            // 0..23
    const int which = nt >> 3;
    const int hh = nt & 7;
    const int n0 = hh * 64;
    const float* bias = (which == 0) ? bq : (which == 1) ? bk : bv;
    const u16* Wsel = Wt + (size_t)which * HD * IN_DIM;

    const int tid = threadIdx.x;
    const int w = tid >> 6, lane = tid & 63, l15 = lane & 15, quad = lane >> 4;
    const int sr = tid >> 2, sc = (tid & 3) * 8;

    f32x4 acc[4];
#pragma unroll
    for (int t = 0; t < 4; ++t) acc[t] = (f32x4){0.f, 0.f, 0.f, 0.f};

    for (int kk = 0; kk < IN_DIM; kk += 32) {
        __syncthreads();
        *(uint4*)&As[sr * GP + sc] = *(const uint4*)(h_bf + (size_t)(m0 + sr) * IN_DIM + kk + sc);
        *(uint4*)&Bs[sr * GP + sc] = *(const uint4*)(Wsel + (size_t)(n0 + sr) * IN_DIM + kk + sc);
        __syncthreads();
        bf16x8 a = *(const bf16x8*)&As[(w * 16 + l15) * GP + quad * 8];
#pragma unroll
        for (int t = 0; t < 4; ++t) {
            bf16x8 b = *(const bf16x8*)&Bs[(t * 16 + l15) * GP + quad * 8];
            acc[t] = __builtin_amdgcn_mfma_f32_16x16x32_bf16(a, b, acc[t], 0, 0, 0);
        }
    }

    const int row_l = w * 16 + quad * 4;
    if (which < 2) {
        u16* Out = (which == 0) ? Qg : Kg;
        const float scale = (which == 0) ? 0.125f : 1.0f;
#pragma unroll
        for (int t = 0; t < 4; ++t) {
            float bvv = bias[n0 + t * 16 + l15];
#pragma unroll
            for (int r = 0; r < 4; ++r) {
                float v = (acc[t][r] + bvv) * scale;
                Out[(size_t)(m0 + row_l + r) * HD + n0 + t * 16 + l15] = f2bf(v);
            }
        }
    } else {
        // V: LDS transpose, then coalesced store of Vt[b][h][d][n]
        u16* T = pool;   // [64][72]
        __syncthreads();
#pragma unroll
        for (int t = 0; t < 4; ++t) {
            float bvv = bias[n0 + t * 16 + l15];
            ushort4 o;
            o.x = f2bf(acc[t][0] + bvv);
            o.y = f2bf(acc[t][1] + bvv);
            o.z = f2bf(acc[t][2] + bvv);
            o.w = f2bf(acc[t][3] + bvv);
            *(ushort4*)&T[(t * 16 + l15) * 72 + row_l] = o;
        }
        __syncthreads();
        const int b = m0 >> 10, nloc = m0 & 1023;
        const int d = tid >> 2, ms = (tid & 3) * 16;
        u16* dst = Vtg + ((size_t)(b * NHEADS + hh) * DH + d) * NSEQ + nloc + ms;
        *(uint4*)(dst)     = *(uint4*)&T[d * 72 + ms];
        *(uint4*)(dst + 8) = *(uint4*)&T[d * 72 + ms + 8];
    }
}

// ============================================================
// Fused masked attention, bf16 MFMA + fp32 online softmax.
// grid (16 q-tiles, 64 b*h), 256 threads (4 waves, 16 q-rows each).
// ============================================================
#define SP2 72   // LDS row stride (u16) = 36 dwords

__global__ __launch_bounds__(256)
void attn_kernel(const int* __restrict__ adj, const u16* __restrict__ Qg,
                 const u16* __restrict__ Kg, const u16* __restrict__ Vtg,
                 float* __restrict__ out)
{
    __shared__ u16 Ks[64 * SP2];
    __shared__ u16 Vs[64 * SP2];   // V^T chunk: [d][m]
    __shared__ u16 Ps[64 * SP2];   // P: [n][m]

    const int tid = threadIdx.x;
    const int w = tid >> 6, lane = tid & 63, l15 = lane & 15, quad = lane >> 4;
    const int qt = blockIdx.x, bh = blockIdx.y;
    const int b = bh >> 3;
    const int n0 = qt * 64;
    const size_t rowbase = (size_t)b * NSEQ;
    const int colbase = (bh & 7) * DH;

    // Q A-fragments straight from global (bf16, pre-scaled by 1/8)
    const u16* qrow = Qg + (rowbase + n0 + w * 16 + l15) * HD + colbase;
    const bf16x8 qa0 = *(const bf16x8*)(qrow + quad * 8);
    const bf16x8 qa1 = *(const bf16x8*)(qrow + 32 + quad * 8);

    const int sr = tid >> 2, sc = (tid & 3) * 16;
    const u16* krow = Kg + (rowbase + sr) * HD + colbase;
    const u16* vrow = Vtg + ((size_t)bh * DH + sr) * NSEQ;

    float mrow[4], lrow[4];
#pragma unroll
    for (int r = 0; r < 4; ++r) { mrow[r] = -INFINITY; lrow[r] = 0.f; }
    f32x4 O[4];
#pragma unroll
    for (int t = 0; t < 4; ++t) O[t] = (f32x4){0.f, 0.f, 0.f, 0.f};

    for (int ch = 0; ch < NSEQ / 64; ++ch) {
        const int m0 = ch * 64;

        // adjacency for this wave's 16 rows x 64 cols — issue early
        int av[16];
        const int* arow = adj + (size_t)(n0 + w * 16 + quad * 4) * NSEQ + m0 + l15;
#pragma unroll
        for (int r = 0; r < 4; ++r)
#pragma unroll
            for (int t = 0; t < 4; ++t)
                av[r * 4 + t] = arow[(size_t)r * NSEQ + t * 16];

        __syncthreads();   // prior chunk's LDS readers done
        {
            const u16* ks = krow + (size_t)m0 * HD + sc;
            *(uint4*)&Ks[sr * SP2 + sc]     = *(const uint4*)(ks);
            *(uint4*)&Ks[sr * SP2 + sc + 8] = *(const uint4*)(ks + 8);
            const u16* vs = vrow + m0 + sc;
            *(uint4*)&Vs[sr * SP2 + sc]     = *(const uint4*)(vs);
            *(uint4*)&Vs[sr * SP2 + sc + 8] = *(const uint4*)(vs + 8);
        }
        __syncthreads();

        // S = Q K^T (pre-scaled), C layout: row=quad*4+r, col=t*16+l15
        f32x4 s4[4];
#pragma unroll
        for (int t = 0; t < 4; ++t) {
            bf16x8 kb0 = *(const bf16x8*)&Ks[(t * 16 + l15) * SP2 + quad * 8];
            bf16x8 kb1 = *(const bf16x8*)&Ks[(t * 16 + l15) * SP2 + 32 + quad * 8];
            f32x4 z = (f32x4){0.f, 0.f, 0.f, 0.f};
            z = __builtin_amdgcn_mfma_f32_16x16x32_bf16(qa0, kb0, z, 0, 0, 0);
            z = __builtin_amdgcn_mfma_f32_16x16x32_bf16(qa1, kb1, z, 0, 0, 0);
            s4[t] = z;
        }
#pragma unroll
        for (int t = 0; t < 4; ++t)
#pragma unroll
            for (int r = 0; r < 4; ++r)
                if (av[r * 4 + t] == 0) s4[t][r] = -INFINITY;

        // online softmax (per row; 16 lanes of a quad are redundant)
        float cm[4];
#pragma unroll
        for (int r = 0; r < 4; ++r)
            cm[r] = fmaxf(fmaxf(s4[0][r], s4[1][r]), fmaxf(s4[2][r], s4[3][r]));
#pragma unroll
        for (int d = 1; d < 16; d <<= 1)
#pragma unroll
            for (int r = 0; r < 4; ++r)
                cm[r] = fmaxf(cm[r], __shfl_xor(cm[r], d, 64));

        float alpha[4], mref[4];
#pragma unroll
        for (int r = 0; r < 4; ++r) {
            float mn = fmaxf(mrow[r], cm[r]);
            alpha[r] = (mrow[r] == -INFINITY) ? 0.f : __expf(mrow[r] - mn);
            mref[r] = (mn == -INFINITY) ? 0.f : mn;
            mrow[r] = mn;
        }

        float rs[4] = {0.f, 0.f, 0.f, 0.f};
        u16 pb[4][4];
#pragma unroll
        for (int t = 0; t < 4; ++t)
#pragma unroll
            for (int r = 0; r < 4; ++r) {
                float p = __expf(s4[t][r] - mref[r]);
                rs[r] += p;
                pb[t][r] = f2bf(p);
            }
#pragma unroll
        for (int d = 1; d < 16; d <<= 1)
#pragma unroll
            for (int r = 0; r < 4; ++r)
                rs[r] += __shfl_xor(rs[r], d, 64);
#pragma unroll
        for (int r = 0; r < 4; ++r) lrow[r] = lrow[r] * alpha[r] + rs[r];

#pragma unroll
        for (int t = 0; t < 4; ++t)
#pragma unroll
            for (int r = 0; r < 4; ++r) O[t][r] *= alpha[r];

        // P -> LDS [n][m] (wave-private rows)
#pragma unroll
        for (int t = 0; t < 4; ++t)
#pragma unroll
            for (int r = 0; r < 4; ++r)
                Ps[(w * 16 + quad * 4 + r) * SP2 + t * 16 + l15] = pb[t][r];
        __syncthreads();

        // O += P V  (A from Ps rows, B from Vs rows — both k-contiguous)
        bf16x8 pa0 = *(const bf16x8*)&Ps[(w * 16 + l15) * SP2 + quad * 8];
        bf16x8 pa1 = *(const bf16x8*)&Ps[(w * 16 + l15) * SP2 + 32 + quad * 8];
#pragma unroll
        for (int t = 0; t < 4; ++t) {
            bf16x8 vb0 = *(const bf16x8*)&Vs[(t * 16 + l15) * SP2 + quad * 8];
            bf16x8 vb1 = *(const bf16x8*)&Vs[(t * 16 + l15) * SP2 + 32 + quad * 8];
            O[t] = __builtin_amdgcn_mfma_f32_16x16x32_bf16(pa0, vb0, O[t], 0, 0, 0);
            O[t] = __builtin_amdgcn_mfma_f32_16x16x32_bf16(pa1, vb1, O[t], 0, 0, 0);
        }
    }

    float inv[4];
#pragma unroll
    for (int r = 0; r < 4; ++r) inv[r] = 1.0f / lrow[r];
#pragma unroll
    for (int t = 0; t < 4; ++t)
#pragma unroll
        for (int r = 0; r < 4; ++r)
            out[(rowbase + n0 + w * 16 + quad * 4 + r) * HD + colbase + t * 16 + l15] =
                O[t][r] * inv[r];
}

// ============================================================
extern "C" void kernel_launch(void* const* d_in, const int* in_sizes, int n_in,
                              void* d_out, int out_size, void* d_ws, size_t ws_size,
                              hipStream_t stream) {
    const int*   adj = (const int*)d_in[0];
    const float* h   = (const float*)d_in[1];
    const float* Wq  = (const float*)d_in[2];
    const float* bq  = (const float*)d_in[3];
    const float* Wk  = (const float*)d_in[4];
    const float* bk  = (const float*)d_in[5];
    const float* Wv  = (const float*)d_in[6];
    const float* bv  = (const float*)d_in[7];
    float* outp = (float*)d_out;

    u16* h_bf = (u16*)d_ws;                                  // 2 Mi u16
    u16* Wt   = h_bf + (size_t)BATCH * NSEQ * IN_DIM;        // 3 x 512*256
    u16* Qg   = Wt + (size_t)3 * HD * IN_DIM;                // 4 Mi u16 each
    u16* Kg   = Qg + (size_t)BATCH * NSEQ * HD;
    u16* Vtg  = Kg + (size_t)BATCH * NSEQ * HD;

    cvt_h_kernel<<<BATCH * NSEQ * IN_DIM / 1024, 256, 0, stream>>>(h, h_bf);
    wtrans_kernel<<<dim3(IN_DIM / 64, HD / 64, 3), 256, 0, stream>>>(Wq, Wk, Wv, Wt);
    qkv_gemm_kernel<<<dim3(BATCH * NSEQ / 64, 24), 256, 0, stream>>>(
        h_bf, Wt, bq, bk, bv, Qg, Kg, Vtg);
    attn_kernel<<<dim3(NSEQ / 64, BATCH * NHEADS), 256, 0, stream>>>(
        adj, Qg, Kg, Vtg, outp);
}

// Round 3
// 143.442 us; speedup vs baseline: 5.5085x; 1.1710x over previous
//
#include <hip/hip_runtime.h>
#include <math.h>

#define IN_DIM 256
#define HD     512   // NUM_HEADS * OUT_DIM
#define NHEADS 8
#define DH     64
#define NSEQ   1024
#define BATCH  8

typedef unsigned short u16;
typedef unsigned int   u32;
typedef unsigned long long u64;
typedef short bf16x8 __attribute__((ext_vector_type(8)));
typedef float f32x4  __attribute__((ext_vector_type(4)));

static __device__ __forceinline__ u16 f2bf(float x) {
    u32 u = __builtin_bit_cast(u32, x);
    u += 0x7FFFu + ((u >> 16) & 1u);     // RNE
    return (u16)(u >> 16);
}
static __device__ __forceinline__ float bf2f(u16 x) {
    return __builtin_bit_cast(float, ((u32)x) << 16);
}
static __device__ __forceinline__ u32 pk(u16 a, u16 b) {
    return (u32)a | ((u32)b << 16);
}

// ============================================================
// Prep 1: h fp32 -> bf16
// ============================================================
__global__ __launch_bounds__(256)
void cvt_h_kernel(const float* __restrict__ h, u16* __restrict__ h_bf) {
    int i = (blockIdx.x * 256 + threadIdx.x) * 4;
    float4 v = *(const float4*)(h + i);
    ushort4 o;
    o.x = f2bf(v.x); o.y = f2bf(v.y); o.z = f2bf(v.z); o.w = f2bf(v.w);
    *(ushort4*)(h_bf + i) = o;
}

// ============================================================
// Prep 2: W [K=256][N=512] fp32 -> Wt [N=512][K=256] bf16 (x3)
// ============================================================
__global__ __launch_bounds__(256)
void wtrans_kernel(const float* __restrict__ Wq, const float* __restrict__ Wk,
                   const float* __restrict__ Wv, u16* __restrict__ Wt) {
    __shared__ float tile[64][65];
    const int k0 = blockIdx.x * 64;
    const int n0 = blockIdx.y * 64;
    const int wsel = blockIdx.z;
    const float* W = (wsel == 0) ? Wq : (wsel == 1) ? Wk : Wv;
    u16* Out = Wt + (size_t)wsel * HD * IN_DIM;

    const int r = threadIdx.x >> 2, c0 = (threadIdx.x & 3) * 16;
#pragma unroll
    for (int j = 0; j < 16; j += 4) {
        float4 v = *(const float4*)(W + (size_t)(k0 + r) * HD + n0 + c0 + j);
        tile[r][c0 + j + 0] = v.x; tile[r][c0 + j + 1] = v.y;
        tile[r][c0 + j + 2] = v.z; tile[r][c0 + j + 3] = v.w;
    }
    __syncthreads();
    const int n = threadIdx.x >> 2, ks = (threadIdx.x & 3) * 16;
    u16 o[16];
#pragma unroll
    for (int j = 0; j < 16; ++j) o[j] = f2bf(tile[ks + j][n]);
    uint4 u0, u1;
    u0.x = pk(o[0], o[1]);  u0.y = pk(o[2], o[3]);
    u0.z = pk(o[4], o[5]);  u0.w = pk(o[6], o[7]);
    u1.x = pk(o[8], o[9]);  u1.y = pk(o[10], o[11]);
    u1.z = pk(o[12], o[13]); u1.w = pk(o[14], o[15]);
    u16* dst = Out + (size_t)(n0 + n) * IN_DIM + k0 + ks;
    *(uint4*)(dst) = u0;
    *(uint4*)(dst + 8) = u1;
}

// ============================================================
// Prep 3: pack adjacency to bits. word f: row f>>6, cols (f&63)*16..+15
// ============================================================
__global__ __launch_bounds__(256)
void adjpack_kernel(const int* __restrict__ adj, u16* __restrict__ adjb) {
    const int f = blockIdx.x * 256 + threadIdx.x;       // 0..65535
    const int* p = adj + (size_t)f * 16;
    u32 bits = 0;
#pragma unroll
    for (int i = 0; i < 16; i += 4) {
        int4 a = *(const int4*)(p + i);
        bits |= (a.x != 0 ? 1u : 0u) << (i + 0);
        bits |= (a.y != 0 ? 1u : 0u) << (i + 1);
        bits |= (a.z != 0 ? 1u : 0u) << (i + 2);
        bits |= (a.w != 0 ? 1u : 0u) << (i + 3);
    }
    adjb[f] = (u16)bits;
}

// ============================================================
// Prep 4: Kmax[bh] = max_n ||K[b,n,h,:]||  (from bf16 Kg)
// ============================================================
__global__ __launch_bounds__(256)
void knorm_kernel(const u16* __restrict__ Kg, float* __restrict__ Kmax) {
    __shared__ float wmax[4];
    const int bh = blockIdx.x;
    const int b = bh >> 3, hh = bh & 7;
    const int tid = threadIdx.x;
    float mx = 0.f;
#pragma unroll
    for (int k = 0; k < 4; ++k) {
        const int row = k * 256 + tid;
        const u16* p = Kg + ((size_t)(b * NSEQ + row)) * HD + hh * DH;
        float s = 0.f;
#pragma unroll
        for (int j = 0; j < 8; ++j) {
            uint4 u = *(const uint4*)(p + j * 8);
            u32 arr[4] = {u.x, u.y, u.z, u.w};
#pragma unroll
            for (int q = 0; q < 4; ++q) {
                float lo = __builtin_bit_cast(float, arr[q] << 16);
                float hi = __builtin_bit_cast(float, arr[q] & 0xFFFF0000u);
                s += lo * lo + hi * hi;
            }
        }
        mx = fmaxf(mx, s);
    }
#pragma unroll
    for (int d = 1; d < 64; d <<= 1) mx = fmaxf(mx, __shfl_xor(mx, d, 64));
    if ((tid & 63) == 0) wmax[tid >> 6] = mx;
    __syncthreads();
    if (tid == 0) {
        float m = fmaxf(fmaxf(wmax[0], wmax[1]), fmaxf(wmax[2], wmax[3]));
        Kmax[bh] = sqrtf(m);
    }
}

// ============================================================
// QKV GEMM: 128x64 tile, BK=64, bf16 MFMA, XOR-swizzled LDS.
// Q pre-scaled 0.125; V written transposed [b][h][d][n].
// ============================================================
__global__ __launch_bounds__(256, 4)
void qkv_gemm_kernel(const u16* __restrict__ h_bf, const u16* __restrict__ Wt,
                     const float* __restrict__ bq, const float* __restrict__ bk,
                     const float* __restrict__ bv,
                     u16* __restrict__ Qg, u16* __restrict__ Kg,
                     u16* __restrict__ Vtg)
{
    __shared__ u16 pool[128 * 64 + 64 * 64];
    u16* As = pool;
    u16* Bs = pool + 128 * 64;

    const int m0 = blockIdx.x * 128;
    const int nt = blockIdx.y;
    const int which = nt >> 3;
    const int hh = nt & 7;
    const int n0 = hh * 64;
    const float* bias = (which == 0) ? bq : (which == 1) ? bk : bv;
    const u16* Wsel = Wt + (size_t)which * HD * IN_DIM;

    const int tid = threadIdx.x;
    const int w = tid >> 6, lane = tid & 63, l15 = lane & 15, quad = lane >> 4;

    f32x4 acc[2][4];
#pragma unroll
    for (int rs = 0; rs < 2; ++rs)
#pragma unroll
        for (int t = 0; t < 4; ++t) acc[rs][t] = (f32x4){0.f, 0.f, 0.f, 0.f};

    const int ar = tid >> 1, ac8 = (tid & 1) * 4;
    const int br = tid >> 2, bc8 = (tid & 3) * 2;
    const int sw = l15 & 7;

    for (int kk = 0; kk < IN_DIM; kk += 64) {
        __syncthreads();
        {
            const u16* srcA = h_bf + (size_t)(m0 + ar) * IN_DIM + kk + ac8 * 8;
#pragma unroll
            for (int i = 0; i < 4; ++i)
                *(uint4*)&As[ar * 64 + (((ac8 + i) ^ (ar & 7)) * 8)] =
                    *(const uint4*)(srcA + i * 8);
            const u16* srcB = Wsel + (size_t)(n0 + br) * IN_DIM + kk + bc8 * 8;
#pragma unroll
            for (int i = 0; i < 2; ++i)
                *(uint4*)&Bs[br * 64 + (((bc8 + i) ^ (br & 7)) * 8)] =
                    *(const uint4*)(srcB + i * 8);
        }
        __syncthreads();
        bf16x8 a[2][2];
#pragma unroll
        for (int rs = 0; rs < 2; ++rs) {
            const int arow = (w * 32 + rs * 16 + l15) * 64;
            a[rs][0] = *(const bf16x8*)&As[arow + ((quad ^ sw) * 8)];
            a[rs][1] = *(const bf16x8*)&As[arow + (((4 + quad) ^ sw) * 8)];
        }
#pragma unroll
        for (int t = 0; t < 4; ++t) {
            const int brow = (t * 16 + l15) * 64;
            bf16x8 b0 = *(const bf16x8*)&Bs[brow + ((quad ^ sw) * 8)];
            bf16x8 b1 = *(const bf16x8*)&Bs[brow + (((4 + quad) ^ sw) * 8)];
#pragma unroll
            for (int rs = 0; rs < 2; ++rs) {
                acc[rs][t] = __builtin_amdgcn_mfma_f32_16x16x32_bf16(a[rs][0], b0, acc[rs][t], 0, 0, 0);
                acc[rs][t] = __builtin_amdgcn_mfma_f32_16x16x32_bf16(a[rs][1], b1, acc[rs][t], 0, 0, 0);
            }
        }
    }

    if (which < 2) {
        u16* Out = (which == 0) ? Qg : Kg;
        const float scale = (which == 0) ? 0.125f : 1.0f;
#pragma unroll
        for (int t = 0; t < 4; ++t) {
            const float bvv = bias[n0 + t * 16 + l15];
#pragma unroll
            for (int rs = 0; rs < 2; ++rs) {
                const int rowb = m0 + w * 32 + rs * 16 + quad * 4;
#pragma unroll
                for (int r = 0; r < 4; ++r)
                    Out[(size_t)(rowb + r) * HD + n0 + t * 16 + l15] =
                        f2bf((acc[rs][t][r] + bvv) * scale);
            }
        }
    } else {
        // V: transpose through LDS, store Vt[b][h][d][n] coalesced
        u16* T = pool;   // [64][128]
        __syncthreads();
#pragma unroll
        for (int t = 0; t < 4; ++t) {
            const float bvv = bias[n0 + t * 16 + l15];
#pragma unroll
            for (int rs = 0; rs < 2; ++rs) {
                ushort4 o;
                o.x = f2bf(acc[rs][t][0] + bvv);
                o.y = f2bf(acc[rs][t][1] + bvv);
                o.z = f2bf(acc[rs][t][2] + bvv);
                o.w = f2bf(acc[rs][t][3] + bvv);
                *(ushort4*)&T[(t * 16 + l15) * 128 + w * 32 + rs * 16 + quad * 4] = o;
            }
        }
        __syncthreads();
        const int b = m0 >> 10, nloc = m0 & 1023;
        const int d = tid >> 2, c = (tid & 3) * 32;
        u16* dst = Vtg + ((size_t)(b * NHEADS + hh) * DH + d) * NSEQ + nloc + c;
#pragma unroll
        for (int i = 0; i < 4; ++i)
            *(uint4*)(dst + i * 8) = *(uint4*)&T[d * 128 + c + i * 8];
    }
}

// ============================================================
// Fused masked attention: bound-based softmax (no online rescale),
// double-buffered K/V LDS, 1 barrier/chunk, XOR-swizzled LDS.
// grid (8 q-tiles of 128, 64 b*h), 512 threads (8 waves x 16 q-rows).
// ============================================================
__global__ __launch_bounds__(512, 4)
void attn_kernel(const u16* __restrict__ adjb, const u16* __restrict__ Qg,
                 const u16* __restrict__ Kg, const u16* __restrict__ Vtg,
                 const float* __restrict__ Kmaxp, float* __restrict__ out)
{
    __shared__ u16 Ks[2][64 * 64];
    __shared__ u16 Vs[2][64 * 64];
    __shared__ u16 Ps[128 * 64];
    __shared__ float mref_lds[128];

    const int tid = threadIdx.x;
    const int w = tid >> 6, lane = tid & 63, l15 = lane & 15, quad = lane >> 4;
    const int qt = blockIdx.x, bh = blockIdx.y;
    const int b = bh >> 3;
    const int n0 = qt * 128;
    const size_t rowbase = (size_t)b * NSEQ;
    const int colbase = (bh & 7) * DH;
    const int sw = l15 & 7;

    // Q A-frags from global (bf16, pre-scaled by 1/8)
    const u16* qrow = Qg + (rowbase + n0 + w * 16 + l15) * HD + colbase;
    const bf16x8 qa0 = *(const bf16x8*)(qrow + quad * 8);
    const bf16x8 qa1 = *(const bf16x8*)(qrow + 32 + quad * 8);

    // staging mapping: 512 thr -> 64 rows x 8 blocks of 8 u16
    const int srow = tid >> 3, c8w = tid & 7;
    const int swc = ((c8w ^ (srow & 7)) * 8);
    const u16* kgp = Kg + (rowbase + srow) * HD + colbase + c8w * 8;
    const u16* vgp = Vtg + ((size_t)bh * DH + srow) * NSEQ + c8w * 8;

    // mref = ||q|| * Kmax  (scores provably <= mref)
    float qn2 = 0.f;
#pragma unroll
    for (int j = 0; j < 8; ++j) {
        float f0 = bf2f((u16)qa0[j]); qn2 += f0 * f0;
        float f1 = bf2f((u16)qa1[j]); qn2 += f1 * f1;
    }
    qn2 += __shfl_xor(qn2, 16, 64);
    qn2 += __shfl_xor(qn2, 32, 64);
    const float Kmaxv = Kmaxp[bh];
    mref_lds[w * 16 + l15] = sqrtf(qn2) * Kmaxv + 1e-3f;

    // stage chunk 0
    uint4 kG = *(const uint4*)(kgp);
    uint4 vG = *(const uint4*)(vgp);
    *(uint4*)&Ks[0][srow * 64 + swc] = kG;
    *(uint4*)&Vs[0][srow * 64 + swc] = vG;
    __syncthreads();

    float mref[4];
#pragma unroll
    for (int r = 0; r < 4; ++r) mref[r] = mref_lds[w * 16 + quad * 4 + r];

    float lrow[4] = {0.f, 0.f, 0.f, 0.f};
    f32x4 O[4];
#pragma unroll
    for (int t = 0; t < 4; ++t) O[t] = (f32x4){0.f, 0.f, 0.f, 0.f};

    const size_t arowbase = (size_t)(n0 + w * 16 + quad * 4) * 64;

    for (int ch = 0; ch < 16; ++ch) {
        const int cur = ch & 1;
        // prefetch next chunk (global -> regs), overlapped with QK
        if (ch < 15) {
            kG = *(const uint4*)(kgp + (size_t)(ch + 1) * 64 * HD);
            vG = *(const uint4*)(vgp + (ch + 1) * 64);
        }
        // adjacency bits: 4 u64 (one per row)
        u64 aw[4];
#pragma unroll
        for (int r = 0; r < 4; ++r)
            aw[r] = *(const u64*)(adjb + arowbase + (size_t)r * 64 + ch * 4);

        // S = Q K^T  (C layout: row=quad*4+r, col=t*16+l15)
        f32x4 s4[4];
#pragma unroll
        for (int t = 0; t < 4; ++t) {
            const int rb = (t * 16 + l15) * 64;
            bf16x8 kb0 = *(const bf16x8*)&Ks[cur][rb + ((quad ^ sw) * 8)];
            bf16x8 kb1 = *(const bf16x8*)&Ks[cur][rb + (((4 + quad) ^ sw) * 8)];
            f32x4 z = (f32x4){0.f, 0.f, 0.f, 0.f};
            z = __builtin_amdgcn_mfma_f32_16x16x32_bf16(qa0, kb0, z, 0, 0, 0);
            z = __builtin_amdgcn_mfma_f32_16x16x32_bf16(qa1, kb1, z, 0, 0, 0);
            s4[t] = z;
        }
        // write next staging to other buffer (no extra barrier)
        if (ch < 15) {
            *(uint4*)&Ks[1 - cur][srow * 64 + swc] = kG;
            *(uint4*)&Vs[1 - cur][srow * 64 + swc] = vG;
        }
        // p = exp(s - mref), masked; accumulate l; P -> LDS (wave-private)
#pragma unroll
        for (int r = 0; r < 4; ++r) {
            const u64 sh = aw[r] >> l15;
            const u32 lo = (u32)sh, hi = (u32)(sh >> 32);
            float p0 = __expf(s4[0][r] - mref[r]); p0 = (lo & 1u)       ? p0 : 0.f;
            float p1 = __expf(s4[1][r] - mref[r]); p1 = (lo & 0x10000u) ? p1 : 0.f;
            float p2 = __expf(s4[2][r] - mref[r]); p2 = (hi & 1u)       ? p2 : 0.f;
            float p3 = __expf(s4[3][r] - mref[r]); p3 = (hi & 0x10000u) ? p3 : 0.f;
            lrow[r] += p0 + p1 + p2 + p3;
            const int q = quad * 4 + r;
            const int prow = (w * 16 + q) * 64;
            const int qs = q & 7, hi3 = l15 >> 3, lo3 = l15 & 7;
            Ps[prow + (((0 + hi3) ^ qs) * 8) + lo3] = f2bf(p0);
            Ps[prow + (((2 + hi3) ^ qs) * 8) + lo3] = f2bf(p1);
            Ps[prow + (((4 + hi3) ^ qs) * 8) + lo3] = f2bf(p2);
            Ps[prow + (((6 + hi3) ^ qs) * 8) + lo3] = f2bf(p3);
        }
        // O += P V   (A from Ps — same-wave rows, no barrier needed)
        {
            const int par = (w * 16 + l15) * 64;
            bf16x8 pa0 = *(const bf16x8*)&Ps[par + ((quad ^ sw) * 8)];
            bf16x8 pa1 = *(const bf16x8*)&Ps[par + (((4 + quad) ^ sw) * 8)];
#pragma unroll
            for (int t = 0; t < 4; ++t) {
                const int rb = (t * 16 + l15) * 64;
                bf16x8 vb0 = *(const bf16x8*)&Vs[cur][rb + ((quad ^ sw) * 8)];
                bf16x8 vb1 = *(const bf16x8*)&Vs[cur][rb + (((4 + quad) ^ sw) * 8)];
                O[t] = __builtin_amdgcn_mfma_f32_16x16x32_bf16(pa0, vb0, O[t], 0, 0, 0);
                O[t] = __builtin_amdgcn_mfma_f32_16x16x32_bf16(pa1, vb1, O[t], 0, 0, 0);
            }
        }
        __syncthreads();
    }

    // final l reduction across the 16 column-lanes
#pragma unroll
    for (int d = 1; d < 16; d <<= 1)
#pragma unroll
        for (int r = 0; r < 4; ++r)
            lrow[r] += __shfl_xor(lrow[r], d, 64);

    float inv[4];
#pragma unroll
    for (int r = 0; r < 4; ++r) inv[r] = 1.0f / lrow[r];
#pragma unroll
    for (int t = 0; t < 4; ++t)
#pragma unroll
        for (int r = 0; r < 4; ++r)
            out[(rowbase + n0 + w * 16 + quad * 4 + r) * HD + colbase + t * 16 + l15] =
                O[t][r] * inv[r];
}

// ============================================================
extern "C" void kernel_launch(void* const* d_in, const int* in_sizes, int n_in,
                              void* d_out, int out_size, void* d_ws, size_t ws_size,
                              hipStream_t stream) {
    const int*   adj = (const int*)d_in[0];
    const float* h   = (const float*)d_in[1];
    const float* Wq  = (const float*)d_in[2];
    const float* bq  = (const float*)d_in[3];
    const float* Wk  = (const float*)d_in[4];
    const float* bk  = (const float*)d_in[5];
    const float* Wv  = (const float*)d_in[6];
    const float* bv  = (const float*)d_in[7];
    float* outp = (float*)d_out;

    u16* h_bf = (u16*)d_ws;                                  // 2 Mi u16
    u16* Wt   = h_bf + (size_t)BATCH * NSEQ * IN_DIM;        // 3 x 512*256
    u16* Qg   = Wt + (size_t)3 * HD * IN_DIM;                // 4 Mi u16 each
    u16* Kg   = Qg + (size_t)BATCH * NSEQ * HD;
    u16* Vtg  = Kg + (size_t)BATCH * NSEQ * HD;
    u16* adjb = Vtg + (size_t)BATCH * NSEQ * HD;             // 65536 u16
    float* Kmax = (float*)(adjb + 65536);                    // 64 floats

    cvt_h_kernel<<<BATCH * NSEQ * IN_DIM / 1024, 256, 0, stream>>>(h, h_bf);
    wtrans_kernel<<<dim3(IN_DIM / 64, HD / 64, 3), 256, 0, stream>>>(Wq, Wk, Wv, Wt);
    adjpack_kernel<<<256, 256, 0, stream>>>(adj, adjb);
    qkv_gemm_kernel<<<dim3(BATCH * NSEQ / 128, 24), 256, 0, stream>>>(
        h_bf, Wt, bq, bk, bv, Qg, Kg, Vtg);
    knorm_kernel<<<64, 256, 0, stream>>>(Kg, Kmax);
    attn_kernel<<<dim3(NSEQ / 128, BATCH * NHEADS), 512, 0, stream>>>(
        adjb, Qg, Kg, Vtg, Kmax, outp);
}